// Round 1
// baseline (246.408 us; speedup 1.0000x reference)
//
#include <hip/hip_runtime.h>
#include <stdint.h>

#define BN 16384
#define DK 1024
#define CN 100
#define CP 112      // padded cols: 7 per thread * 16 threads
#define NJ 7        // cols per thread
#define NI 4        // rows per thread
#define KC 32       // k-chunk
#define ROWS 64     // rows per block
#define NCHUNK (DK / KC)

// ---------------- init ----------------
__global__ void k_init(unsigned long long* packed, int* counts, float* ce_sum,
                       float* term_sum, int* present, float* G_class, float* Mm) {
    int i = blockIdx.x * 256 + threadIdx.x;
    if (i < CN * CN) { G_class[i] = 0.f; Mm[i] = 0.f; }
    if (i < CN) { packed[i] = ~0ULL; counts[i] = 0; }
    if (i == 0) { *ce_sum = 0.f; *term_sum = 0.f; *present = 0; }
}

// ---------------- main: x@W + softmax + class reductions ----------------
__global__ __launch_bounds__(256) void k_main(
    const float* __restrict__ x, const float* __restrict__ W,
    const int* __restrict__ y, float* __restrict__ g_buf,
    float* __restrict__ G_class, unsigned long long* __restrict__ packed,
    int* __restrict__ counts, float* __restrict__ ce_sum) {
    __shared__ float x_ld[ROWS][KC + 4];   // +4 pad keeps float4 align & kills bank conflicts
    __shared__ float w_ld[KC][CP];
    __shared__ float red[256];

    const int tid = threadIdx.x;
    const int tc  = tid & 15;    // column group 0..15
    const int tr  = tid >> 4;    // row group 0..15
    const int row0 = blockIdx.x * ROWS;

    // x staging: 2 float4 per thread. idx = tid (+256): r = idx>>3, kq = (idx&7)*4
    const int xr0 = tid >> 3;
    const int xkq = (tid & 7) * 4;
    const float* xg0 = x + (size_t)(row0 + xr0) * DK + xkq;
    const float* xg1 = x + (size_t)(row0 + xr0 + 32) * DK + xkq;

    // w staging: 14 scalars per thread; flat LDS idx = tid + 256*t = k*CP + c
    int woff[14];
#pragma unroll
    for (int t = 0; t < 14; ++t) {
        int idx = tid + 256 * t;
        int k = idx / CP;
        int c = idx - k * CP;
        woff[t] = (c < CN) ? (k * CN + c) : -1;
    }

    float acc[NI][NJ];
#pragma unroll
    for (int i = 0; i < NI; ++i)
#pragma unroll
        for (int j = 0; j < NJ; ++j) acc[i][j] = 0.f;

    float4 xs0, xs1;
    float wst[14];

    // prologue: chunk 0 -> regs
    xs0 = *(const float4*)xg0;
    xs1 = *(const float4*)xg1;
#pragma unroll
    for (int t = 0; t < 14; ++t) wst[t] = (woff[t] >= 0) ? W[woff[t]] : 0.f;

    for (int ch = 0; ch < NCHUNK; ++ch) {
        __syncthreads();
        // commit staged regs to LDS
        *(float4*)&x_ld[xr0][xkq]      = xs0;
        *(float4*)&x_ld[xr0 + 32][xkq] = xs1;
#pragma unroll
        for (int t = 0; t < 14; ++t) ((float*)w_ld)[tid + 256 * t] = wst[t];
        __syncthreads();
        // prefetch next chunk (overlaps compute below)
        if (ch + 1 < NCHUNK) {
            const float* xp0 = xg0 + (ch + 1) * KC;
            const float* xp1 = xg1 + (ch + 1) * KC;
            xs0 = *(const float4*)xp0;
            xs1 = *(const float4*)xp1;
            const float* wp = W + (size_t)(ch + 1) * KC * CN;
#pragma unroll
            for (int t = 0; t < 14; ++t) wst[t] = (woff[t] >= 0) ? wp[woff[t]] : 0.f;
        }
        // compute this chunk
#pragma unroll
        for (int k4 = 0; k4 < KC / 4; ++k4) {
            float4 xv[NI];
#pragma unroll
            for (int i = 0; i < NI; ++i)
                xv[i] = *(const float4*)&x_ld[tr + 16 * i][k4 * 4];
#pragma unroll
            for (int kk = 0; kk < 4; ++kk) {
                float wv[NJ];
#pragma unroll
                for (int j = 0; j < NJ; ++j) wv[j] = w_ld[k4 * 4 + kk][tc + 16 * j];
#pragma unroll
                for (int i = 0; i < NI; ++i) {
                    float xvk = (kk == 0) ? xv[i].x : (kk == 1) ? xv[i].y
                              : (kk == 2) ? xv[i].z : xv[i].w;
#pragma unroll
                    for (int j = 0; j < NJ; ++j)
                        acc[i][j] = fmaf(xvk, wv[j], acc[i][j]);
                }
            }
        }
    }

    // fused softmax + g + class reductions. Row r = tr+16*i owned by 16 lanes (tc).
    float ce_acc = 0.f;
#pragma unroll
    for (int i = 0; i < NI; ++i) {
        const int r = tr + 16 * i;
        const int grow = row0 + r;
        const int yr = y[grow];
        float m = -3.4e38f;
#pragma unroll
        for (int j = 0; j < NJ; ++j) {
            int c = tc + 16 * j;
            if (c < CN) m = fmaxf(m, acc[i][j]);
        }
#pragma unroll
        for (int s = 1; s < 16; s <<= 1) m = fmaxf(m, __shfl_xor(m, s));
        float ev[NJ];
        float ssum = 0.f;
#pragma unroll
        for (int j = 0; j < NJ; ++j) {
            int c = tc + 16 * j;
            ev[j] = (c < CN) ? __expf(acc[i][j] - m) : 0.f;
            ssum += ev[j];
        }
#pragma unroll
        for (int s = 1; s < 16; s <<= 1) ssum += __shfl_xor(ssum, s);
        const float lse = m + __logf(ssum);
        const float inv = 1.f / ssum;
        float ly = 0.f;
        bool own = false;
#pragma unroll
        for (int j = 0; j < NJ; ++j) {
            int c = tc + 16 * j;
            if (c < CN) {
                float g = ev[j] * inv - ((c == yr) ? 1.f : 0.f);
                g_buf[(size_t)grow * CN + c] = g;
                atomicAdd(&G_class[yr * CN + c], g);
                if (c == yr) { ly = acc[i][j]; own = true; }
            }
        }
        if (own) {
            float ce = lse - ly;   // ce >= 0 always
            ce_acc += ce;
            unsigned long long pk =
                ((unsigned long long)__float_as_uint(ce) << 32) | (unsigned int)grow;
            atomicMin(&packed[yr], pk);   // min ce; ties -> lowest row idx (jnp.argmin)
            atomicAdd(&counts[yr], 1);
        }
    }
    red[tid] = ce_acc;
    __syncthreads();
    for (int s = 128; s > 0; s >>= 1) {
        if (tid < s) red[tid] += red[tid + s];
        __syncthreads();
    }
    if (tid == 0) atomicAdd(ce_sum, red[0]);
}

// ---------------- Gram matrix M = W^T W (100x100) ----------------
__global__ __launch_bounds__(128) void k_gram(const float* __restrict__ W,
                                              float* __restrict__ Mm) {
    const int c1 = blockIdx.x;
    const int kb = blockIdx.y;
    const int c2 = threadIdx.x;
    if (c2 >= CN) return;
    float s = 0.f;
    const float* w1 = W + (size_t)kb * 128 * CN + c1;
    const float* w2 = W + (size_t)kb * 128 * CN + c2;
#pragma unroll 8
    for (int k = 0; k < 128; ++k) s = fmaf(w1[k * CN], w2[k * CN], s);
    atomicAdd(&Mm[c1 * CN + c2], s);
}

// ---------------- per-class cosines via quadratic forms ----------------
__global__ __launch_bounds__(128) void k_class(
    const float* __restrict__ g_buf, const float* __restrict__ G_class,
    const float* __restrict__ Mm, const unsigned long long* __restrict__ packed,
    const int* __restrict__ counts, float* __restrict__ term_sum,
    int* __restrict__ present) {
    __shared__ float a_s[CN], p_s[CN], n_s[CN];
    __shared__ float wsum[2][5];
    const int cp = blockIdx.x;
    const int t = threadIdx.x;
    const int cnt = counts[cp];
    if (cnt == 0) return;   // absent class: masked out (uniform exit, no barriers yet)
    const int anchor = (int)(packed[cp] & 0xffffffffULL);
    if (t < CN) {
        float a = g_buf[(size_t)anchor * CN + t];
        float cs = G_class[cp * CN + t];
        float tot = 0.f;
#pragma unroll 4
        for (int k = 0; k < CN; ++k) tot += G_class[k * CN + t];
        a_s[t] = a;
        p_s[t] = cs - a;      // class_sum - grad_a  (C-space)
        n_s[t] = tot - cs;    // total - class_sum   (C-space)
    }
    __syncthreads();
    float aa = 0, ap = 0, pp = 0, an = 0, nn = 0;
    if (t < CN) {
        float va = 0, vp = 0, vn = 0;
#pragma unroll 4
        for (int k = 0; k < CN; ++k) {
            float mm = Mm[t * CN + k];
            va = fmaf(mm, a_s[k], va);
            vp = fmaf(mm, p_s[k], vp);
            vn = fmaf(mm, n_s[k], vn);
        }
        float av = a_s[t], pv = p_s[t], nv = n_s[t];
        aa = av * va; ap = av * vp; pp = pv * vp; an = av * vn; nn = nv * vn;
    }
#pragma unroll
    for (int s = 1; s < 64; s <<= 1) {
        aa += __shfl_xor(aa, s); ap += __shfl_xor(ap, s); pp += __shfl_xor(pp, s);
        an += __shfl_xor(an, s); nn += __shfl_xor(nn, s);
    }
    const int wid = t >> 6, lane = t & 63;
    if (lane == 0) {
        wsum[wid][0] = aa; wsum[wid][1] = ap; wsum[wid][2] = pp;
        wsum[wid][3] = an; wsum[wid][4] = nn;
    }
    __syncthreads();
    if (t == 0) {
        aa = wsum[0][0] + wsum[1][0];
        ap = wsum[0][1] + wsum[1][1];
        pp = wsum[0][2] + wsum[1][2];
        an = wsum[0][3] + wsum[1][3];
        nn = wsum[0][4] + wsum[1][4];
        float na  = sqrtf(fmaxf(aa, 0.f));
        float np_ = sqrtf(fmaxf(pp, 0.f));
        float nn_ = sqrtf(fmaxf(nn, 0.f));
        float cos_ap = ap / (fmaxf(na, 1e-12f) * fmaxf(np_, 1e-12f));
        float cos_an = an / (fmaxf(na, 1e-12f) * fmaxf(nn_, 1e-12f));
        atomicAdd(term_sum, cos_ap - cos_an);
        atomicAdd(present, 1);
    }
}

// ---------------- final scalar ----------------
__global__ void k_final(const float* ce_sum, const float* term_sum,
                        const int* present, float* out) {
    float npres = fmaxf((float)(*present), 1.f);
    out[0] = (*ce_sum) * (1.f / (float)BN) - 2.0f * ((*term_sum) / npres);
}

extern "C" void kernel_launch(void* const* d_in, const int* in_sizes, int n_in,
                              void* d_out, int out_size, void* d_ws, size_t ws_size,
                              hipStream_t stream) {
    const float* x = (const float*)d_in[0];
    const float* W = (const float*)d_in[1];
    const int* y = (const int*)d_in[2];

    char* ws = (char*)d_ws;
    unsigned long long* packed = (unsigned long long*)ws;          //   800 B
    int*   counts   = (int*)(ws + 800);                            //   400 B
    float* ce_sum   = (float*)(ws + 1200);
    float* term_sum = (float*)(ws + 1204);
    int*   present  = (int*)(ws + 1208);
    float* G_class  = (float*)(ws + 1280);                         // 40000 B
    float* Mm       = (float*)(ws + 41280);                        // 40000 B
    float* g_buf    = (float*)(ws + 81280);                        // BN*CN*4 = 6.55 MB

    k_init<<<(CN * CN + 255) / 256, 256, 0, stream>>>(packed, counts, ce_sum,
                                                      term_sum, present, G_class, Mm);
    k_main<<<BN / ROWS, 256, 0, stream>>>(x, W, y, g_buf, G_class, packed, counts, ce_sum);
    k_gram<<<dim3(CN, 8), 128, 0, stream>>>(W, Mm);
    k_class<<<CN, 128, 0, stream>>>(g_buf, G_class, Mm, packed, counts, term_sum, present);
    k_final<<<1, 1, 0, stream>>>(ce_sum, term_sum, present, (float*)d_out);
}